// Round 10
// baseline (341.538 us; speedup 1.0000x reference)
//
#include <hip/hip_runtime.h>
#include <hip/hip_fp16.h>
#include <cstdint>
#include <cstddef>

#define N_NODES_C 100000
#define N_EDGES_C 1250000
#define N_PAIRS_C 200000
#define IN_DIM_C 128
#define HID_C 64

// graph-build geometry
#define NB_S 256
#define BSH 9
#define NPB 512
#define NBKT 196
#define SEG_CAP 8192

typedef _Float16 f16x8 __attribute__((ext_vector_type(8)));
typedef float f32x4 __attribute__((ext_vector_type(4)));

// ---------------- scan helpers ----------------

#define SCAN_TPB 256
#define SCAN_IPT 4
#define SCAN_ELEMS 1024

__global__ void k_scan_partial(const int* __restrict__ in, int* __restrict__ outp,
                               int* __restrict__ blocksums, int n) {
    __shared__ int sd[SCAN_TPB];
    int tid = threadIdx.x;
    int base = blockIdx.x * SCAN_ELEMS + tid * SCAN_IPT;
    int v[SCAN_IPT]; int s = 0;
    for (int k = 0; k < SCAN_IPT; k++) { int idx = base + k; v[k] = (idx < n) ? in[idx] : 0; s += v[k]; }
    sd[tid] = s;
    __syncthreads();
    for (int off = 1; off < SCAN_TPB; off <<= 1) {
        int t = (tid >= off) ? sd[tid - off] : 0;
        __syncthreads();
        sd[tid] += t;
        __syncthreads();
    }
    int excl = sd[tid] - s;
    for (int k = 0; k < SCAN_IPT; k++) { int idx = base + k; if (idx < n) outp[idx] = excl; excl += v[k]; }
    if (tid == SCAN_TPB - 1) blocksums[blockIdx.x] = sd[tid];
}

__global__ void k_scan_blocks(int* __restrict__ bs, int nb) {
    __shared__ int sd[128];
    int t = threadIdx.x;
    int v = (t < nb) ? bs[t] : 0;
    sd[t] = v;
    __syncthreads();
    for (int off = 1; off < 128; off <<= 1) {
        int u = (t >= off) ? sd[t - off] : 0;
        __syncthreads();
        sd[t] += u;
        __syncthreads();
    }
    if (t < nb) bs[t] = sd[t] - v;
}

__global__ void k_scan_addg(int* __restrict__ arr, const int* __restrict__ bs, int n) {
    int i = blockIdx.x * blockDim.x + threadIdx.x;
    if (i < n) arr[i] += bs[i >> 10];
}

// ---------------- graph build: two-level counting sort ----------------

__global__ __launch_bounds__(256) void k_hist(const int* __restrict__ dst,
                                              int* __restrict__ histT, int e) {
    __shared__ int lh[NBKT];
    int tid = threadIdx.x, k = blockIdx.x;
    if (tid < NBKT) lh[tid] = 0;
    __syncthreads();
    int chunk = (e + NB_S - 1) / NB_S;
    int i0 = k * chunk, i1 = min(i0 + chunk, e);
    for (int i = i0 + tid; i < i1; i += 256) atomicAdd(&lh[dst[i] >> BSH], 1);
    __syncthreads();
    if (tid < NBKT) histT[tid * NB_S + k] = lh[tid];
}

__global__ __launch_bounds__(256) void k_scatter(const int* __restrict__ edges,
                                                 const int* __restrict__ offs,
                                                 int2* __restrict__ staging, int e) {
    __shared__ int cur[NBKT];
    int tid = threadIdx.x, k = blockIdx.x;
    if (tid < NBKT) cur[tid] = offs[tid * NB_S + k];
    __syncthreads();
    int chunk = (e + NB_S - 1) / NB_S;
    int i0 = k * chunk, i1 = min(i0 + chunk, e);
    for (int i = i0 + tid; i < i1; i += 256) {
        int s = edges[i];
        int d = edges[e + i];
        int p = atomicAdd(&cur[d >> BSH], 1);
        staging[p] = make_int2(s, d);
    }
}

__global__ __launch_bounds__(256) void k_bucket_fill(const int2* __restrict__ staging,
        const int* __restrict__ offs, int* __restrict__ rowptr,
        float* __restrict__ invd, int* __restrict__ adj, int n, int e) {
    __shared__ int ldeg[NPB];
    __shared__ int lrow[NPB];
    __shared__ int ps[256];
    __shared__ int lseg[SEG_CAP];
    int tid = threadIdx.x, b = blockIdx.x;
    int n0 = b << BSH;
    int nn = min(NPB, n - n0);
    int segBeg = offs[b * NB_S];
    int segEnd = (b == NBKT - 1) ? e : offs[(b + 1) * NB_S];

    ldeg[tid] = 0; ldeg[tid + 256] = 0;
    __syncthreads();
    for (int i = segBeg + tid; i < segEnd; i += 256)
        atomicAdd(&ldeg[staging[i].y - n0], 1);
    __syncthreads();

    int a0 = ldeg[2 * tid], a1 = ldeg[2 * tid + 1];
    int s = a0 + a1;
    ps[tid] = s;
    __syncthreads();
    for (int off = 1; off < 256; off <<= 1) {
        int t = (tid >= off) ? ps[tid - off] : 0;
        __syncthreads();
        ps[tid] += t;
        __syncthreads();
    }
    int excl = ps[tid] - s;
    lrow[2 * tid] = excl;
    lrow[2 * tid + 1] = excl + a0;
    __syncthreads();

    for (int j = tid; j < nn; j += 256) {
        rowptr[n0 + j] = segBeg + lrow[j];
        int d = ldeg[j];
        invd[n0 + j] = (d > 0) ? (1.0f / (float)d) : 0.0f;
    }
    if (b == NBKT - 1 && tid == 0) rowptr[n] = e;
    __syncthreads();

    for (int i = segBeg + tid; i < segEnd; i += 256) {
        int2 ed = staging[i];
        int p = atomicAdd(&lrow[ed.y - n0], 1);
        if (p < SEG_CAP) lseg[p] = ed.x;
        else adj[segBeg + p] = ed.x;
    }
    __syncthreads();

    int m = segEnd - segBeg; if (m > SEG_CAP) m = SEG_CAP;
    for (int p = tid; p < m; p += 256) adj[segBeg + p] = lseg[p];
}

// ---------------- aggregation ----------------
// fp16-gather, TWO NODES PER WAVE (R8 win: 50->36 us). Lanes 0-31 = node A,
// lanes 32-63 = node B; each lane owns 2 cols via __half2. Writes fp16 agg
// directly (feeds the MFMA GEMM).
// History: R4 fusion 3.2x worse (concurrency-bound); R5 instruction shave
// neutral (was memory-bound); R7 fp16 gather -8%; R8 2-nodes/wave -20%.

__global__ __launch_bounds__(256) void k_aggregate(const int* __restrict__ rowptr,
        const int* __restrict__ adj, const float* __restrict__ invd,
        const __half* __restrict__ hin16, __half* __restrict__ agg16, int n) {
    int wid = threadIdx.x >> 6, lane = threadIdx.x & 63;
    int nodeA = (blockIdx.x * 4 + wid) * 2;
    if (nodeA >= n) return;
    const int half_ = lane >> 5;       // 0: node A, 1: node B
    const int c2 = (lane & 31) * 2;    // columns c2, c2+1
    int node = nodeA + half_;
    bool valid = node < n;
    int nodec = valid ? node : n - 1;
    int beg = rowptr[nodec], end = rowptr[nodec + 1];
    float accx = 0.f, accy = 0.f;
    for (int e = beg; e < end; e += 8) {
        int idx[8];
        #pragma unroll
        for (int j = 0; j < 8; ++j) {
            int ee = e + j;
            idx[j] = adj[ee < end ? ee : end - 1];
        }
        __half2 v[8];
        #pragma unroll
        for (int j = 0; j < 8; ++j)
            v[j] = *(const __half2*)&hin16[(size_t)idx[j] * HID_C + c2];
        #pragma unroll
        for (int j = 0; j < 8; ++j) {
            float2 f = __half22float2(v[j]);
            bool in = (e + j < end);
            accx += in ? f.x : 0.f;
            accy += in ? f.y : 0.f;
        }
    }
    if (valid) {
        float s = invd[node];
        *(__half2*)&agg16[(size_t)node * HID_C + c2] =
            __floats2half2_rn(accx * s, accy * s);
    }
}

// ---------------- helpers ----------------

__device__ __forceinline__ float4 ld4(const float* p) { return *(const float4*)p; }

// ---------------- k_mm: MFMA fp16 GEMM (enc + layers) ------------------------
// R9 PROVEN (409->341 us, absmax unchanged). out = relu(A @ W + b), K=128,
// BM=128 x BN=64, 4 waves, mfma_f32_16x16x32_f16, 48 KB LDS.
// A/B staged with the SAME assumed k-octet map -> HW k-permutation cancels;
// C/D layout col=lane&15, row=(lane>>4)*4+reg (HW-verified).
// SRC 0: A = x (f32, stride 128, converted in staging), W = Ws1 (128x64)
// SRC 1: A = [agg16 | h16] (fp16, stride 64 each), W = [Ws1;Ws2] (64x64 each)

template<int SRC>
__global__ __launch_bounds__(256, 2) void k_mm(
    const float* __restrict__ A1f,
    const __half* __restrict__ A1h, const __half* __restrict__ A2h,
    const float* __restrict__ Ws1, const float* __restrict__ Ws2,
    const float* __restrict__ bias,
    float* __restrict__ outp, __half* __restrict__ out16, int nrows)
{
    __shared__ __half Ah[128 * 128];  // [row][k-swizzled], 32 KB
    __shared__ __half Bt[64 * 128];   // [col][k-swizzled], 16 KB
    const int t = threadIdx.x;
    const int g0 = blockIdx.x * 128;

    #pragma unroll
    for (int p = 0; p < 8; ++p) {
        int li = p * 256 + t;
        int r = li >> 4;              // 0..127
        int o = li & 15;              // octet
        int g = g0 + r; if (g > nrows - 1) g = nrows - 1;
        f16x8 v;
        if (SRC == 0) {
            const float* src = A1f + (size_t)g * 128 + o * 8;
            float4 f0 = ld4(src), f1 = ld4(src + 4);
            v[0] = (_Float16)f0.x; v[1] = (_Float16)f0.y;
            v[2] = (_Float16)f0.z; v[3] = (_Float16)f0.w;
            v[4] = (_Float16)f1.x; v[5] = (_Float16)f1.y;
            v[6] = (_Float16)f1.z; v[7] = (_Float16)f1.w;
        } else {
            const __half* src = (o < 8) ? (A1h + (size_t)g * 64 + o * 8)
                                        : (A2h + (size_t)g * 64 + (o - 8) * 8);
            v = *(const f16x8*)src;
        }
        *(f16x8*)&Ah[r * 128 + (o ^ (r & 15)) * 8] = v;
    }
    #pragma unroll
    for (int p = 0; p < 32; ++p) {
        int li = p * 256 + t;
        int c = li & 63;
        int k = li >> 6;              // 0..127
        float wv;
        if (SRC == 0) wv = Ws1[k * 64 + c];
        else          wv = (k < 64) ? Ws1[k * 64 + c] : Ws2[(k - 64) * 64 + c];
        Bt[c * 128 + (((k >> 3) ^ (c & 15)) * 8) + (k & 7)] = __float2half(wv);
    }
    __syncthreads();

    const int lane = t & 63;
    const int wid = t >> 6;
    const int R = wid * 32;           // wave's 32-row strip
    const int lr = lane & 15;
    const int lk = lane >> 4;         // octet-within-K-step

    f32x4 acc[2][4];
    #pragma unroll
    for (int fr = 0; fr < 2; ++fr)
        #pragma unroll
        for (int fc = 0; fc < 4; ++fc)
            acc[fr][fc] = (f32x4){0.f, 0.f, 0.f, 0.f};

    #pragma unroll
    for (int ks = 0; ks < 4; ++ks) {
        int o = ks * 4 + lk;          // octet 0..15
        f16x8 af0, af1;
        {
            int r0 = R + lr;
            int r1 = R + 16 + lr;
            af0 = *(const f16x8*)&Ah[r0 * 128 + (o ^ (r0 & 15)) * 8];
            af1 = *(const f16x8*)&Ah[r1 * 128 + (o ^ (r1 & 15)) * 8];
        }
        #pragma unroll
        for (int fc = 0; fc < 4; ++fc) {
            int c = fc * 16 + lr;
            f16x8 bf = *(const f16x8*)&Bt[c * 128 + (o ^ (c & 15)) * 8];
            acc[0][fc] = __builtin_amdgcn_mfma_f32_16x16x32_f16(af0, bf, acc[0][fc], 0, 0, 0);
            acc[1][fc] = __builtin_amdgcn_mfma_f32_16x16x32_f16(af1, bf, acc[1][fc], 0, 0, 0);
        }
    }

    float bv[4];
    #pragma unroll
    for (int fc = 0; fc < 4; ++fc) bv[fc] = bias[fc * 16 + lr];
    #pragma unroll
    for (int fr = 0; fr < 2; ++fr) {
        #pragma unroll
        for (int j = 0; j < 4; ++j) {
            int gr = g0 + R + fr * 16 + lk * 4 + j;
            if (gr < nrows) {
                #pragma unroll
                for (int fc = 0; fc < 4; ++fc) {
                    int col = fc * 16 + lr;
                    float v = fmaxf(acc[fr][fc][j] + bv[fc], 0.f);
                    outp[(size_t)gr * 64 + col] = v;
                    if (out16) out16[(size_t)gr * 64 + col] = __float2half(v);
                }
            }
        }
    }
}

// ---------------- k_uvm: MFMA fp16 UV GEMM (pred path) -----------------------
// Replaces the f32 k_uv (42 us @ 13.9% occupancy, 64 KB LDS — last f32 GEMM).
// U|V = h @ [W1_top | W1_bot]: K=64, tile 128 rows x 128 cols, 4 waves, each
// 32 rows x 128 cols = 2x8 frags x 2 K-steps = 32 MFMA. LDS Ah[128][64] +
// Bt[128][64] fp16 = 32 KB -> 2x the occupancy of k_uv. Octet swizzle
// o^(r&7) (2-way banks, free). A converted f32->fp16 in staging (same
// quantization class as the accepted h16 path); U/V outputs stay f32 and
// k_pred is untouched. Same shared-k-map cancellation as k_mm.

__global__ __launch_bounds__(256, 2) void k_uvm(
    const float* __restrict__ H, const float* __restrict__ W1,
    float* __restrict__ U, float* __restrict__ V, int nrows)
{
    __shared__ __half Ah[128 * 64];   // [row][k^sw], 16 KB
    __shared__ __half Bt[128 * 64];   // [col][k^sw], 16 KB
    const int t = threadIdx.x;
    const int g0 = blockIdx.x * 128;

    // stage A: 128 rows x 8 octets, f32 -> fp16
    #pragma unroll
    for (int p = 0; p < 4; ++p) {
        int li = p * 256 + t;         // 0..1023
        int r = li >> 3;              // 0..127
        int o = li & 7;               // octet 0..7
        int g = g0 + r; if (g > nrows - 1) g = nrows - 1;
        const float* src = H + (size_t)g * 64 + o * 8;
        float4 f0 = ld4(src), f1 = ld4(src + 4);
        f16x8 v;
        v[0] = (_Float16)f0.x; v[1] = (_Float16)f0.y;
        v[2] = (_Float16)f0.z; v[3] = (_Float16)f0.w;
        v[4] = (_Float16)f1.x; v[5] = (_Float16)f1.y;
        v[6] = (_Float16)f1.z; v[7] = (_Float16)f1.w;
        *(f16x8*)&Ah[r * 64 + (o ^ (r & 7)) * 8] = v;
    }
    // stage Bt[c][k]: c<64 -> W1[k][c] (U), c>=64 -> W1[64+k][c-64] (V)
    #pragma unroll
    for (int p = 0; p < 32; ++p) {
        int li = p * 256 + t;         // 0..8191
        int c = li >> 6;              // 0..127
        int k = li & 63;
        float wv = (c < 64) ? W1[k * 64 + c] : W1[(64 + k) * 64 + (c - 64)];
        Bt[c * 64 + (((k >> 3) ^ (c & 7)) * 8) + (k & 7)] = __float2half(wv);
    }
    __syncthreads();

    const int lane = t & 63;
    const int wid = t >> 6;
    const int R = wid * 32;           // wave's 32-row strip
    const int lr = lane & 15;
    const int lk = lane >> 4;

    f32x4 acc[2][8];
    #pragma unroll
    for (int fr = 0; fr < 2; ++fr)
        #pragma unroll
        for (int fc = 0; fc < 8; ++fc)
            acc[fr][fc] = (f32x4){0.f, 0.f, 0.f, 0.f};

    #pragma unroll
    for (int ks = 0; ks < 2; ++ks) {
        int o = ks * 4 + lk;          // octet 0..7
        int r0 = R + lr, r1 = R + 16 + lr;
        f16x8 af0 = *(const f16x8*)&Ah[r0 * 64 + (o ^ (r0 & 7)) * 8];
        f16x8 af1 = *(const f16x8*)&Ah[r1 * 64 + (o ^ (r1 & 7)) * 8];
        #pragma unroll
        for (int fc = 0; fc < 8; ++fc) {
            int c = fc * 16 + lr;
            f16x8 bf = *(const f16x8*)&Bt[c * 64 + (o ^ (c & 7)) * 8];
            acc[0][fc] = __builtin_amdgcn_mfma_f32_16x16x32_f16(af0, bf, acc[0][fc], 0, 0, 0);
            acc[1][fc] = __builtin_amdgcn_mfma_f32_16x16x32_f16(af1, bf, acc[1][fc], 0, 0, 0);
        }
    }

    // epilogue: fc<4 -> U, fc>=4 -> V (compile-time after unroll)
    #pragma unroll
    for (int fr = 0; fr < 2; ++fr) {
        #pragma unroll
        for (int j = 0; j < 4; ++j) {
            int gr = g0 + R + fr * 16 + lk * 4 + j;
            if (gr < nrows) {
                #pragma unroll
                for (int fc = 0; fc < 8; ++fc) {
                    int col = fc * 16 + lr;
                    float v = acc[fr][fc][j];
                    if (col < 64) U[(size_t)gr * 64 + col] = v;
                    else          V[(size_t)gr * 64 + (col - 64)] = v;
                }
            }
        }
    }
}

// k_pred: out[p] = relu(U[a] + V[b] + b1) . W2 + b2 — pure gather-reduce.
// 16 lanes per pair, 256 B coalesced row per gather, shfl-reduce width 16.
__global__ __launch_bounds__(256) void k_pred(
    const float* __restrict__ U, const float* __restrict__ V,
    const int* __restrict__ pidx, const float* __restrict__ b1,
    const float* __restrict__ W2, const float* __restrict__ b2,
    float* __restrict__ outp, int np)
{
    const int t = threadIdx.x;
    const int lg = t & 15;
    const int p = blockIdx.x * 16 + (t >> 4);
    float4 bv = ld4(b1 + lg * 4);
    float4 wv = ld4(W2 + lg * 4);
    if (p >= np) return;
    int2 ab = ((const int2*)pidx)[p];
    float4 u = ld4(U + (size_t)ab.x * 64 + lg * 4);
    float4 v = ld4(V + (size_t)ab.y * 64 + lg * 4);
    float zx = fmaxf(u.x + v.x + bv.x, 0.f);
    float zy = fmaxf(u.y + v.y + bv.y, 0.f);
    float zz = fmaxf(u.z + v.z + bv.z, 0.f);
    float zw = fmaxf(u.w + v.w + bv.w, 0.f);
    float s = zx * wv.x + zy * wv.y + zz * wv.z + zw * wv.w;
    s += __shfl_down(s, 8, 16);
    s += __shfl_down(s, 4, 16);
    s += __shfl_down(s, 2, 16);
    s += __shfl_down(s, 1, 16);
    if (lg == 0) outp[p] = s + b2[0];
}

// ---------------- launch ----------------

extern "C" void kernel_launch(void* const* d_in, const int* in_sizes, int n_in,
                              void* d_out, int out_size, void* d_ws, size_t ws_size,
                              hipStream_t stream) {
    const float* x    = (const float*)d_in[0];
    const int*   edges= (const int*)d_in[1];
    const int*   pair = (const int*)d_in[2];
    const float* encW = (const float*)d_in[3];
    const float* encb = (const float*)d_in[4];
    const float* Wl   = (const float*)d_in[5];
    const float* bl   = (const float*)d_in[6];
    const float* Wr   = (const float*)d_in[7];
    const float* W1   = (const float*)d_in[8];
    const float* b1   = (const float*)d_in[9];
    const float* W2   = (const float*)d_in[10];
    const float* b2   = (const float*)d_in[11];
    float* out = (float*)d_out;

    const int N = N_NODES_C, E = N_EDGES_C, P = N_PAIRS_C;
    const int* dst = edges + E;
    const int M = NBKT * NB_S;

    char* w = (char*)d_ws;
    auto alloc = [&](size_t bytes) { char* p = w; w += (bytes + 255) & ~(size_t)255; return p; };
    int*   rowptr = (int*)alloc((size_t)(N + 1) * 4);
    int*   histT  = (int*)alloc((size_t)M * 4);
    int*   offs   = (int*)alloc((size_t)M * 4);
    int*   bsums  = (int*)alloc(128 * 4);
    float* invd   = (float*)alloc((size_t)N * 4);
    int*   adj    = (int*)alloc((size_t)E * 4);
    float* h0     = (float*)alloc((size_t)N * HID_C * 4);
    float* h1     = (float*)alloc((size_t)N * HID_C * 4);
    float* agg    = (float*)alloc((size_t)N * HID_C * 4);
    __half* h16a  = (__half*)alloc((size_t)N * HID_C * 2);
    __half* h16b  = (__half*)alloc((size_t)N * HID_C * 2);
    __half* agg16 = (__half*)alloc((size_t)N * HID_C * 2);
    int2*  staging= (int2*)agg;

    int nscan = (M + SCAN_ELEMS - 1) / SCAN_ELEMS;

    hipLaunchKernelGGL(k_hist, dim3(NB_S), dim3(256), 0, stream, dst, histT, E);
    hipLaunchKernelGGL(k_scan_partial, dim3(nscan), dim3(SCAN_TPB), 0, stream, histT, offs, bsums, M);
    hipLaunchKernelGGL(k_scan_blocks, dim3(1), dim3(128), 0, stream, bsums, nscan);
    hipLaunchKernelGGL(k_scan_addg, dim3((M + 255) / 256), dim3(256), 0, stream, offs, bsums, M);
    hipLaunchKernelGGL(k_scatter, dim3(NB_S), dim3(256), 0, stream, edges, offs, staging, E);
    hipLaunchKernelGGL(k_bucket_fill, dim3(NBKT), dim3(256), 0, stream, staging, offs, rowptr, invd, adj, N, E);

    const int NB128 = (N + 127) / 128;

    // encoder: MFMA fp16 (x converted in staging)
    k_mm<0><<<dim3(NB128), dim3(256), 0, stream>>>(
        x, nullptr, nullptr, encW, nullptr, encb, h0, h16a, N);

    float* hc = h0; float* hn = h1;
    __half* h16c = h16a; __half* h16n = h16b;
    for (int l = 0; l < 3; l++) {
        hipLaunchKernelGGL(k_aggregate, dim3((N / 2 + 3) / 4), dim3(256), 0, stream,
                           rowptr, adj, invd, h16c, agg16, N);
        // layer 2 (l==2) output never feeds another aggregate: skip fp16 mirror
        k_mm<1><<<dim3(NB128), dim3(256), 0, stream>>>(
            nullptr, agg16, h16c, Wl + (size_t)l * 64 * 64, Wr + (size_t)l * 64 * 64,
            bl + (size_t)l * 64, hn, (l < 2) ? h16n : (__half*)nullptr, N);
        float* tswap = hc; hc = hn; hn = tswap;
        __half* t16 = h16c; h16c = h16n; h16n = t16;
    }

    // pred path: UV = h @ [W1_top | W1_bot] (MFMA fp16), then gather-reduce.
    float* Ubuf = agg;
    float* Vbuf = hn;
    const int NB_UV = (N + 127) / 128;
    hipLaunchKernelGGL(k_uvm, dim3(NB_UV), dim3(256), 0, stream, hc, W1, Ubuf, Vbuf, N);
    hipLaunchKernelGGL(k_pred, dim3((P + 15) / 16), dim3(256), 0, stream,
                       Ubuf, Vbuf, pair, b1, W2, b2, out, P);
}

// Round 11
// 329.751 us; speedup vs baseline: 1.0357x; 1.0357x over previous
//
#include <hip/hip_runtime.h>
#include <hip/hip_fp16.h>
#include <cstdint>
#include <cstddef>

#define N_NODES_C 100000
#define N_EDGES_C 1250000
#define N_PAIRS_C 200000
#define IN_DIM_C 128
#define HID_C 64

// graph-build geometry
#define NB_S 256
#define BSH 9
#define NPB 512
#define NBKT 196
#define SEG_CAP 8192

typedef _Float16 f16x8 __attribute__((ext_vector_type(8)));
typedef float f32x4 __attribute__((ext_vector_type(4)));

// ---------------- scan helpers ----------------

#define SCAN_TPB 256
#define SCAN_IPT 4
#define SCAN_ELEMS 1024

__global__ void k_scan_partial(const int* __restrict__ in, int* __restrict__ outp,
                               int* __restrict__ blocksums, int n) {
    __shared__ int sd[SCAN_TPB];
    int tid = threadIdx.x;
    int base = blockIdx.x * SCAN_ELEMS + tid * SCAN_IPT;
    int v[SCAN_IPT]; int s = 0;
    for (int k = 0; k < SCAN_IPT; k++) { int idx = base + k; v[k] = (idx < n) ? in[idx] : 0; s += v[k]; }
    sd[tid] = s;
    __syncthreads();
    for (int off = 1; off < SCAN_TPB; off <<= 1) {
        int t = (tid >= off) ? sd[tid - off] : 0;
        __syncthreads();
        sd[tid] += t;
        __syncthreads();
    }
    int excl = sd[tid] - s;
    for (int k = 0; k < SCAN_IPT; k++) { int idx = base + k; if (idx < n) outp[idx] = excl; excl += v[k]; }
    if (tid == SCAN_TPB - 1) blocksums[blockIdx.x] = sd[tid];
}

__global__ void k_scan_blocks(int* __restrict__ bs, int nb) {
    __shared__ int sd[128];
    int t = threadIdx.x;
    int v = (t < nb) ? bs[t] : 0;
    sd[t] = v;
    __syncthreads();
    for (int off = 1; off < 128; off <<= 1) {
        int u = (t >= off) ? sd[t - off] : 0;
        __syncthreads();
        sd[t] += u;
        __syncthreads();
    }
    if (t < nb) bs[t] = sd[t] - v;
}

__global__ void k_scan_addg(int* __restrict__ arr, const int* __restrict__ bs, int n) {
    int i = blockIdx.x * blockDim.x + threadIdx.x;
    if (i < n) arr[i] += bs[i >> 10];
}

// ---------------- graph build: two-level counting sort ----------------

__global__ __launch_bounds__(256) void k_hist(const int* __restrict__ dst,
                                              int* __restrict__ histT, int e) {
    __shared__ int lh[NBKT];
    int tid = threadIdx.x, k = blockIdx.x;
    if (tid < NBKT) lh[tid] = 0;
    __syncthreads();
    int chunk = (e + NB_S - 1) / NB_S;
    int i0 = k * chunk, i1 = min(i0 + chunk, e);
    for (int i = i0 + tid; i < i1; i += 256) atomicAdd(&lh[dst[i] >> BSH], 1);
    __syncthreads();
    if (tid < NBKT) histT[tid * NB_S + k] = lh[tid];
}

__global__ __launch_bounds__(256) void k_scatter(const int* __restrict__ edges,
                                                 const int* __restrict__ offs,
                                                 int2* __restrict__ staging, int e) {
    __shared__ int cur[NBKT];
    int tid = threadIdx.x, k = blockIdx.x;
    if (tid < NBKT) cur[tid] = offs[tid * NB_S + k];
    __syncthreads();
    int chunk = (e + NB_S - 1) / NB_S;
    int i0 = k * chunk, i1 = min(i0 + chunk, e);
    for (int i = i0 + tid; i < i1; i += 256) {
        int s = edges[i];
        int d = edges[e + i];
        int p = atomicAdd(&cur[d >> BSH], 1);
        staging[p] = make_int2(s, d);
    }
}

__global__ __launch_bounds__(256) void k_bucket_fill(const int2* __restrict__ staging,
        const int* __restrict__ offs, int* __restrict__ rowptr,
        float* __restrict__ invd, int* __restrict__ adj, int n, int e) {
    __shared__ int ldeg[NPB];
    __shared__ int lrow[NPB];
    __shared__ int ps[256];
    __shared__ int lseg[SEG_CAP];
    int tid = threadIdx.x, b = blockIdx.x;
    int n0 = b << BSH;
    int nn = min(NPB, n - n0);
    int segBeg = offs[b * NB_S];
    int segEnd = (b == NBKT - 1) ? e : offs[(b + 1) * NB_S];

    ldeg[tid] = 0; ldeg[tid + 256] = 0;
    __syncthreads();
    for (int i = segBeg + tid; i < segEnd; i += 256)
        atomicAdd(&ldeg[staging[i].y - n0], 1);
    __syncthreads();

    int a0 = ldeg[2 * tid], a1 = ldeg[2 * tid + 1];
    int s = a0 + a1;
    ps[tid] = s;
    __syncthreads();
    for (int off = 1; off < 256; off <<= 1) {
        int t = (tid >= off) ? ps[tid - off] : 0;
        __syncthreads();
        ps[tid] += t;
        __syncthreads();
    }
    int excl = ps[tid] - s;
    lrow[2 * tid] = excl;
    lrow[2 * tid + 1] = excl + a0;
    __syncthreads();

    for (int j = tid; j < nn; j += 256) {
        rowptr[n0 + j] = segBeg + lrow[j];
        int d = ldeg[j];
        invd[n0 + j] = (d > 0) ? (1.0f / (float)d) : 0.0f;
    }
    if (b == NBKT - 1 && tid == 0) rowptr[n] = e;
    __syncthreads();

    for (int i = segBeg + tid; i < segEnd; i += 256) {
        int2 ed = staging[i];
        int p = atomicAdd(&lrow[ed.y - n0], 1);
        if (p < SEG_CAP) lseg[p] = ed.x;
        else adj[segBeg + p] = ed.x;
    }
    __syncthreads();

    int m = segEnd - segBeg; if (m > SEG_CAP) m = SEG_CAP;
    for (int p = tid; p < m; p += 256) adj[segBeg + p] = lseg[p];
}

// ---------------- aggregation ----------------
// fp16-gather, FOUR NODES PER WAVE (extends the proven R7/R8 ladder:
// 50 f32 -> 46 fp16 -> 36 two-node -> this). 16 lanes per node, each lane
// owns 4 cols via one 8-byte load (float2 holding 4 halves); 16 x 8 B = full
// 128 B row. One gather-load instruction serves FOUR edges (one per quarter)
// -> load-issues + addressing per edge halved again vs R8. cvt/add FLOPs
// unchanged. Masked-iteration cost: loop to max of 4 Poisson(12.5) degrees.
// R4 fusion and R5 instruction-shave history: see journal — gather needs
// high occupancy; only fewer-bytes or fewer-issues move it.

__global__ __launch_bounds__(256) void k_aggregate(const int* __restrict__ rowptr,
        const int* __restrict__ adj, const float* __restrict__ invd,
        const __half* __restrict__ hin16, __half* __restrict__ agg16, int n) {
    int wid = threadIdx.x >> 6, lane = threadIdx.x & 63;
    int node0 = (blockIdx.x * 4 + wid) * 4;   // 4 nodes per wave
    if (node0 >= n) return;
    const int q = lane >> 4;          // quarter 0..3 -> node slot
    const int c4 = (lane & 15) * 4;   // columns c4..c4+3
    int node = node0 + q;
    bool valid = node < n;
    int nodec = valid ? node : n - 1;
    int beg = rowptr[nodec], end = rowptr[nodec + 1];
    float a0 = 0.f, a1 = 0.f, a2 = 0.f, a3 = 0.f;
    for (int e = beg; e < end; e += 8) {
        int idx[8];
        #pragma unroll
        for (int j = 0; j < 8; ++j) {
            int ee = e + j;
            idx[j] = adj[ee < end ? ee : end - 1];
        }
        float2 raw[8];
        #pragma unroll
        for (int j = 0; j < 8; ++j)
            raw[j] = *(const float2*)&hin16[(size_t)idx[j] * HID_C + c4];
        #pragma unroll
        for (int j = 0; j < 8; ++j) {
            union { float f; __half2 h; } ulo, uhi;
            ulo.f = raw[j].x; uhi.f = raw[j].y;
            float2 f0 = __half22float2(ulo.h);
            float2 f1 = __half22float2(uhi.h);
            bool in = (e + j < end);
            a0 += in ? f0.x : 0.f;
            a1 += in ? f0.y : 0.f;
            a2 += in ? f1.x : 0.f;
            a3 += in ? f1.y : 0.f;
        }
    }
    if (valid) {
        float s = invd[node];
        union { float f; __half2 h; } s0, s1;
        s0.h = __floats2half2_rn(a0 * s, a1 * s);
        s1.h = __floats2half2_rn(a2 * s, a3 * s);
        *(float2*)&agg16[(size_t)node * HID_C + c4] = make_float2(s0.f, s1.f);
    }
}

// ---------------- helpers ----------------

__device__ __forceinline__ float4 ld4(const float* p) { return *(const float4*)p; }

// ---------------- k_mm: MFMA fp16 GEMM (enc + layers) ------------------------
// R9 PROVEN (409->341 us, absmax unchanged). out = relu(A @ W + b), K=128,
// BM=128 x BN=64, 4 waves, mfma_f32_16x16x32_f16, 48 KB LDS.
// A/B staged with the SAME assumed k-octet map -> HW k-permutation cancels;
// C/D layout col=lane&15, row=(lane>>4)*4+reg (HW-verified).
// SRC 0: A = x (f32, stride 128, converted in staging), W = Ws1 (128x64)
// SRC 1: A = [agg16 | h16] (fp16, stride 64 each), W = [Ws1;Ws2] (64x64 each)

template<int SRC>
__global__ __launch_bounds__(256, 2) void k_mm(
    const float* __restrict__ A1f,
    const __half* __restrict__ A1h, const __half* __restrict__ A2h,
    const float* __restrict__ Ws1, const float* __restrict__ Ws2,
    const float* __restrict__ bias,
    float* __restrict__ outp, __half* __restrict__ out16, int nrows)
{
    __shared__ __half Ah[128 * 128];  // [row][k-swizzled], 32 KB
    __shared__ __half Bt[64 * 128];   // [col][k-swizzled], 16 KB
    const int t = threadIdx.x;
    const int g0 = blockIdx.x * 128;

    #pragma unroll
    for (int p = 0; p < 8; ++p) {
        int li = p * 256 + t;
        int r = li >> 4;              // 0..127
        int o = li & 15;              // octet
        int g = g0 + r; if (g > nrows - 1) g = nrows - 1;
        f16x8 v;
        if (SRC == 0) {
            const float* src = A1f + (size_t)g * 128 + o * 8;
            float4 f0 = ld4(src), f1 = ld4(src + 4);
            v[0] = (_Float16)f0.x; v[1] = (_Float16)f0.y;
            v[2] = (_Float16)f0.z; v[3] = (_Float16)f0.w;
            v[4] = (_Float16)f1.x; v[5] = (_Float16)f1.y;
            v[6] = (_Float16)f1.z; v[7] = (_Float16)f1.w;
        } else {
            const __half* src = (o < 8) ? (A1h + (size_t)g * 64 + o * 8)
                                        : (A2h + (size_t)g * 64 + (o - 8) * 8);
            v = *(const f16x8*)src;
        }
        *(f16x8*)&Ah[r * 128 + (o ^ (r & 15)) * 8] = v;
    }
    #pragma unroll
    for (int p = 0; p < 32; ++p) {
        int li = p * 256 + t;
        int c = li & 63;
        int k = li >> 6;              // 0..127
        float wv;
        if (SRC == 0) wv = Ws1[k * 64 + c];
        else          wv = (k < 64) ? Ws1[k * 64 + c] : Ws2[(k - 64) * 64 + c];
        Bt[c * 128 + (((k >> 3) ^ (c & 15)) * 8) + (k & 7)] = __float2half(wv);
    }
    __syncthreads();

    const int lane = t & 63;
    const int wid = t >> 6;
    const int R = wid * 32;           // wave's 32-row strip
    const int lr = lane & 15;
    const int lk = lane >> 4;         // octet-within-K-step

    f32x4 acc[2][4];
    #pragma unroll
    for (int fr = 0; fr < 2; ++fr)
        #pragma unroll
        for (int fc = 0; fc < 4; ++fc)
            acc[fr][fc] = (f32x4){0.f, 0.f, 0.f, 0.f};

    #pragma unroll
    for (int ks = 0; ks < 4; ++ks) {
        int o = ks * 4 + lk;          // octet 0..15
        f16x8 af0, af1;
        {
            int r0 = R + lr;
            int r1 = R + 16 + lr;
            af0 = *(const f16x8*)&Ah[r0 * 128 + (o ^ (r0 & 15)) * 8];
            af1 = *(const f16x8*)&Ah[r1 * 128 + (o ^ (r1 & 15)) * 8];
        }
        #pragma unroll
        for (int fc = 0; fc < 4; ++fc) {
            int c = fc * 16 + lr;
            f16x8 bf = *(const f16x8*)&Bt[c * 128 + (o ^ (c & 15)) * 8];
            acc[0][fc] = __builtin_amdgcn_mfma_f32_16x16x32_f16(af0, bf, acc[0][fc], 0, 0, 0);
            acc[1][fc] = __builtin_amdgcn_mfma_f32_16x16x32_f16(af1, bf, acc[1][fc], 0, 0, 0);
        }
    }

    float bv[4];
    #pragma unroll
    for (int fc = 0; fc < 4; ++fc) bv[fc] = bias[fc * 16 + lr];
    #pragma unroll
    for (int fr = 0; fr < 2; ++fr) {
        #pragma unroll
        for (int j = 0; j < 4; ++j) {
            int gr = g0 + R + fr * 16 + lk * 4 + j;
            if (gr < nrows) {
                #pragma unroll
                for (int fc = 0; fc < 4; ++fc) {
                    int col = fc * 16 + lr;
                    float v = fmaxf(acc[fr][fc][j] + bv[fc], 0.f);
                    outp[(size_t)gr * 64 + col] = v;
                    if (out16) out16[(size_t)gr * 64 + col] = __float2half(v);
                }
            }
        }
    }
}

// ---------------- k_uvm: MFMA fp16 UV GEMM (pred path) -----------------------
// R10 landed ~40 us (total flat) — audit found Bt staging was UNCOALESCED
// (c = li>>6, k = li&63: lanes stepped k at stride 256 B). R11 fixes:
// (1) c = li&127, k = li>>7 -> lanes read contiguous W1 rows (k_mm's proven
// pattern); (2) U/V written as fp16 (halves write traffic 51->25.6 MB and
// k_pred's gather traffic). K=64, tile 128x128, 4 waves, 32 KB LDS, octet
// swizzle o^(r&7); same shared-k-map cancellation + HW-verified C/D layout.

__global__ __launch_bounds__(256, 2) void k_uvm(
    const float* __restrict__ H, const float* __restrict__ W1,
    __half* __restrict__ U16, __half* __restrict__ V16, int nrows)
{
    __shared__ __half Ah[128 * 64];   // [row][k^sw], 16 KB
    __shared__ __half Bt[128 * 64];   // [col][k^sw], 16 KB
    const int t = threadIdx.x;
    const int g0 = blockIdx.x * 128;

    // stage A: 128 rows x 8 octets, f32 -> fp16
    #pragma unroll
    for (int p = 0; p < 4; ++p) {
        int li = p * 256 + t;         // 0..1023
        int r = li >> 3;              // 0..127
        int o = li & 7;               // octet 0..7
        int g = g0 + r; if (g > nrows - 1) g = nrows - 1;
        const float* src = H + (size_t)g * 64 + o * 8;
        float4 f0 = ld4(src), f1 = ld4(src + 4);
        f16x8 v;
        v[0] = (_Float16)f0.x; v[1] = (_Float16)f0.y;
        v[2] = (_Float16)f0.z; v[3] = (_Float16)f0.w;
        v[4] = (_Float16)f1.x; v[5] = (_Float16)f1.y;
        v[6] = (_Float16)f1.z; v[7] = (_Float16)f1.w;
        *(f16x8*)&Ah[r * 64 + (o ^ (r & 7)) * 8] = v;
    }
    // stage Bt[c][k]: c<64 -> W1[k][c] (U), c>=64 -> W1[64+k][c-64] (V).
    // COALESCED: consecutive lanes step c (contiguous W1 row halves).
    #pragma unroll
    for (int p = 0; p < 32; ++p) {
        int li = p * 256 + t;         // 0..8191 = k*128 + c
        int c = li & 127;
        int k = li >> 7;              // 0..63
        float wv = (c < 64) ? W1[k * 64 + c] : W1[(64 + k) * 64 + (c - 64)];
        Bt[c * 64 + (((k >> 3) ^ (c & 7)) * 8) + (k & 7)] = __float2half(wv);
    }
    __syncthreads();

    const int lane = t & 63;
    const int wid = t >> 6;
    const int R = wid * 32;           // wave's 32-row strip
    const int lr = lane & 15;
    const int lk = lane >> 4;

    f32x4 acc[2][8];
    #pragma unroll
    for (int fr = 0; fr < 2; ++fr)
        #pragma unroll
        for (int fc = 0; fc < 8; ++fc)
            acc[fr][fc] = (f32x4){0.f, 0.f, 0.f, 0.f};

    #pragma unroll
    for (int ks = 0; ks < 2; ++ks) {
        int o = ks * 4 + lk;          // octet 0..7
        int r0 = R + lr, r1 = R + 16 + lr;
        f16x8 af0 = *(const f16x8*)&Ah[r0 * 64 + (o ^ (r0 & 7)) * 8];
        f16x8 af1 = *(const f16x8*)&Ah[r1 * 64 + (o ^ (r1 & 7)) * 8];
        #pragma unroll
        for (int fc = 0; fc < 8; ++fc) {
            int c = fc * 16 + lr;
            f16x8 bf = *(const f16x8*)&Bt[c * 64 + (o ^ (c & 7)) * 8];
            acc[0][fc] = __builtin_amdgcn_mfma_f32_16x16x32_f16(af0, bf, acc[0][fc], 0, 0, 0);
            acc[1][fc] = __builtin_amdgcn_mfma_f32_16x16x32_f16(af1, bf, acc[1][fc], 0, 0, 0);
        }
    }

    // epilogue: fc<4 -> U16, fc>=4 -> V16 (fp16 stores)
    #pragma unroll
    for (int fr = 0; fr < 2; ++fr) {
        #pragma unroll
        for (int j = 0; j < 4; ++j) {
            int gr = g0 + R + fr * 16 + lk * 4 + j;
            if (gr < nrows) {
                #pragma unroll
                for (int fc = 0; fc < 8; ++fc) {
                    int col = fc * 16 + lr;
                    __half v = __float2half(acc[fr][fc][j]);
                    if (col < 64) U16[(size_t)gr * 64 + col] = v;
                    else          V16[(size_t)gr * 64 + (col - 64)] = v;
                }
            }
        }
    }
}

// k_pred: out[p] = relu(U[a] + V[b] + b1) . W2 + b2 — pure gather-reduce.
// fp16 U/V rows (128 B): 16 lanes x 8 B = full row. b1/W2/accum stay f32.
__global__ __launch_bounds__(256) void k_pred(
    const __half* __restrict__ U16, const __half* __restrict__ V16,
    const int* __restrict__ pidx, const float* __restrict__ b1,
    const float* __restrict__ W2, const float* __restrict__ b2,
    float* __restrict__ outp, int np)
{
    const int t = threadIdx.x;
    const int lg = t & 15;
    const int p = blockIdx.x * 16 + (t >> 4);
    float4 bv = ld4(b1 + lg * 4);
    float4 wv = ld4(W2 + lg * 4);
    if (p >= np) return;
    int2 ab = ((const int2*)pidx)[p];
    float2 ur = *(const float2*)&U16[(size_t)ab.x * 64 + lg * 4];
    float2 vr = *(const float2*)&V16[(size_t)ab.y * 64 + lg * 4];
    union { float f; __half2 h; } u0, u1, v0, v1;
    u0.f = ur.x; u1.f = ur.y; v0.f = vr.x; v1.f = vr.y;
    float2 ua = __half22float2(u0.h), ub = __half22float2(u1.h);
    float2 va = __half22float2(v0.h), vb = __half22float2(v1.h);
    float zx = fmaxf(ua.x + va.x + bv.x, 0.f);
    float zy = fmaxf(ua.y + va.y + bv.y, 0.f);
    float zz = fmaxf(ub.x + vb.x + bv.z, 0.f);
    float zw = fmaxf(ub.y + vb.y + bv.w, 0.f);
    float s = zx * wv.x + zy * wv.y + zz * wv.z + zw * wv.w;
    s += __shfl_down(s, 8, 16);
    s += __shfl_down(s, 4, 16);
    s += __shfl_down(s, 2, 16);
    s += __shfl_down(s, 1, 16);
    if (lg == 0) outp[p] = s + b2[0];
}

// ---------------- launch ----------------

extern "C" void kernel_launch(void* const* d_in, const int* in_sizes, int n_in,
                              void* d_out, int out_size, void* d_ws, size_t ws_size,
                              hipStream_t stream) {
    const float* x    = (const float*)d_in[0];
    const int*   edges= (const int*)d_in[1];
    const int*   pair = (const int*)d_in[2];
    const float* encW = (const float*)d_in[3];
    const float* encb = (const float*)d_in[4];
    const float* Wl   = (const float*)d_in[5];
    const float* bl   = (const float*)d_in[6];
    const float* Wr   = (const float*)d_in[7];
    const float* W1   = (const float*)d_in[8];
    const float* b1   = (const float*)d_in[9];
    const float* W2   = (const float*)d_in[10];
    const float* b2   = (const float*)d_in[11];
    float* out = (float*)d_out;

    const int N = N_NODES_C, E = N_EDGES_C, P = N_PAIRS_C;
    const int* dst = edges + E;
    const int M = NBKT * NB_S;

    char* w = (char*)d_ws;
    auto alloc = [&](size_t bytes) { char* p = w; w += (bytes + 255) & ~(size_t)255; return p; };
    int*   rowptr = (int*)alloc((size_t)(N + 1) * 4);
    int*   histT  = (int*)alloc((size_t)M * 4);
    int*   offs   = (int*)alloc((size_t)M * 4);
    int*   bsums  = (int*)alloc(128 * 4);
    float* invd   = (float*)alloc((size_t)N * 4);
    int*   adj    = (int*)alloc((size_t)E * 4);
    float* h0     = (float*)alloc((size_t)N * HID_C * 4);
    float* h1     = (float*)alloc((size_t)N * HID_C * 4);
    float* agg    = (float*)alloc((size_t)N * HID_C * 4);
    __half* h16a  = (__half*)alloc((size_t)N * HID_C * 2);
    __half* h16b  = (__half*)alloc((size_t)N * HID_C * 2);
    __half* agg16 = (__half*)alloc((size_t)N * HID_C * 2);
    __half* U16   = (__half*)alloc((size_t)N * HID_C * 2);
    __half* V16   = (__half*)alloc((size_t)N * HID_C * 2);
    int2*  staging= (int2*)agg;

    int nscan = (M + SCAN_ELEMS - 1) / SCAN_ELEMS;

    hipLaunchKernelGGL(k_hist, dim3(NB_S), dim3(256), 0, stream, dst, histT, E);
    hipLaunchKernelGGL(k_scan_partial, dim3(nscan), dim3(SCAN_TPB), 0, stream, histT, offs, bsums, M);
    hipLaunchKernelGGL(k_scan_blocks, dim3(1), dim3(128), 0, stream, bsums, nscan);
    hipLaunchKernelGGL(k_scan_addg, dim3((M + 255) / 256), dim3(256), 0, stream, offs, bsums, M);
    hipLaunchKernelGGL(k_scatter, dim3(NB_S), dim3(256), 0, stream, edges, offs, staging, E);
    hipLaunchKernelGGL(k_bucket_fill, dim3(NBKT), dim3(256), 0, stream, staging, offs, rowptr, invd, adj, N, E);

    const int NB128 = (N + 127) / 128;

    // encoder: MFMA fp16 (x converted in staging)
    k_mm<0><<<dim3(NB128), dim3(256), 0, stream>>>(
        x, nullptr, nullptr, encW, nullptr, encb, h0, h16a, N);

    float* hc = h0; float* hn = h1;
    __half* h16c = h16a; __half* h16n = h16b;
    for (int l = 0; l < 3; l++) {
        // 4 nodes per wave -> 16 nodes per block
        hipLaunchKernelGGL(k_aggregate, dim3((N + 15) / 16), dim3(256), 0, stream,
                           rowptr, adj, invd, h16c, agg16, N);
        // layer 2 (l==2) output never feeds another aggregate: skip fp16 mirror
        k_mm<1><<<dim3(NB128), dim3(256), 0, stream>>>(
            nullptr, agg16, h16c, Wl + (size_t)l * 64 * 64, Wr + (size_t)l * 64 * 64,
            bl + (size_t)l * 64, hn, (l < 2) ? h16n : (__half*)nullptr, N);
        float* tswap = hc; hc = hn; hn = tswap;
        __half* t16 = h16c; h16c = h16n; h16n = t16;
    }

    // pred path: UV = h @ [W1_top | W1_bot] (MFMA fp16, fp16 out), gather-reduce.
    const int NB_UV = (N + 127) / 128;
    hipLaunchKernelGGL(k_uvm, dim3(NB_UV), dim3(256), 0, stream, hc, W1, U16, V16, N);
    hipLaunchKernelGGL(k_pred, dim3((P + 15) / 16), dim3(256), 0, stream,
                       U16, V16, pair, b1, W2, b2, out, P);
}

// Round 12
// 303.001 us; speedup vs baseline: 1.1272x; 1.0883x over previous
//
#include <hip/hip_runtime.h>
#include <hip/hip_fp16.h>
#include <cstdint>
#include <cstddef>

#define N_NODES_C 100000
#define N_EDGES_C 1250000
#define N_PAIRS_C 200000
#define IN_DIM_C 128
#define HID_C 64

// graph-build geometry
#define NB_S 256
#define BSH 9
#define NPB 512
#define NBKT 196
#define SEG_CAP 8192

typedef _Float16 f16x8 __attribute__((ext_vector_type(8)));
typedef float f32x4 __attribute__((ext_vector_type(4)));

// ---------------- scan helpers ----------------

#define SCAN_TPB 256
#define SCAN_IPT 4
#define SCAN_ELEMS 1024

__global__ void k_scan_partial(const int* __restrict__ in, int* __restrict__ outp,
                               int* __restrict__ blocksums, int n) {
    __shared__ int sd[SCAN_TPB];
    int tid = threadIdx.x;
    int base = blockIdx.x * SCAN_ELEMS + tid * SCAN_IPT;
    int v[SCAN_IPT]; int s = 0;
    for (int k = 0; k < SCAN_IPT; k++) { int idx = base + k; v[k] = (idx < n) ? in[idx] : 0; s += v[k]; }
    sd[tid] = s;
    __syncthreads();
    for (int off = 1; off < SCAN_TPB; off <<= 1) {
        int t = (tid >= off) ? sd[tid - off] : 0;
        __syncthreads();
        sd[tid] += t;
        __syncthreads();
    }
    int excl = sd[tid] - s;
    for (int k = 0; k < SCAN_IPT; k++) { int idx = base + k; if (idx < n) outp[idx] = excl; excl += v[k]; }
    if (tid == SCAN_TPB - 1) blocksums[blockIdx.x] = sd[tid];
}

__global__ void k_scan_blocks(int* __restrict__ bs, int nb) {
    __shared__ int sd[128];
    int t = threadIdx.x;
    int v = (t < nb) ? bs[t] : 0;
    sd[t] = v;
    __syncthreads();
    for (int off = 1; off < 128; off <<= 1) {
        int u = (t >= off) ? sd[t - off] : 0;
        __syncthreads();
        sd[t] += u;
        __syncthreads();
    }
    if (t < nb) bs[t] = sd[t] - v;
}

__global__ void k_scan_addg(int* __restrict__ arr, const int* __restrict__ bs, int n) {
    int i = blockIdx.x * blockDim.x + threadIdx.x;
    if (i < n) arr[i] += bs[i >> 10];
}

// ---------------- graph build: two-level counting sort ----------------

__global__ __launch_bounds__(256) void k_hist(const int* __restrict__ dst,
                                              int* __restrict__ histT, int e) {
    __shared__ int lh[NBKT];
    int tid = threadIdx.x, k = blockIdx.x;
    if (tid < NBKT) lh[tid] = 0;
    __syncthreads();
    int chunk = (e + NB_S - 1) / NB_S;
    int i0 = k * chunk, i1 = min(i0 + chunk, e);
    for (int i = i0 + tid; i < i1; i += 256) atomicAdd(&lh[dst[i] >> BSH], 1);
    __syncthreads();
    if (tid < NBKT) histT[tid * NB_S + k] = lh[tid];
}

__global__ __launch_bounds__(256) void k_scatter(const int* __restrict__ edges,
                                                 const int* __restrict__ offs,
                                                 int2* __restrict__ staging, int e) {
    __shared__ int cur[NBKT];
    int tid = threadIdx.x, k = blockIdx.x;
    if (tid < NBKT) cur[tid] = offs[tid * NB_S + k];
    __syncthreads();
    int chunk = (e + NB_S - 1) / NB_S;
    int i0 = k * chunk, i1 = min(i0 + chunk, e);
    for (int i = i0 + tid; i < i1; i += 256) {
        int s = edges[i];
        int d = edges[e + i];
        int p = atomicAdd(&cur[d >> BSH], 1);
        staging[p] = make_int2(s, d);
    }
}

__global__ __launch_bounds__(256) void k_bucket_fill(const int2* __restrict__ staging,
        const int* __restrict__ offs, int* __restrict__ rowptr,
        float* __restrict__ invd, int* __restrict__ adj, int n, int e) {
    __shared__ int ldeg[NPB];
    __shared__ int lrow[NPB];
    __shared__ int ps[256];
    __shared__ int lseg[SEG_CAP];
    int tid = threadIdx.x, b = blockIdx.x;
    int n0 = b << BSH;
    int nn = min(NPB, n - n0);
    int segBeg = offs[b * NB_S];
    int segEnd = (b == NBKT - 1) ? e : offs[(b + 1) * NB_S];

    ldeg[tid] = 0; ldeg[tid + 256] = 0;
    __syncthreads();
    for (int i = segBeg + tid; i < segEnd; i += 256)
        atomicAdd(&ldeg[staging[i].y - n0], 1);
    __syncthreads();

    int a0 = ldeg[2 * tid], a1 = ldeg[2 * tid + 1];
    int s = a0 + a1;
    ps[tid] = s;
    __syncthreads();
    for (int off = 1; off < 256; off <<= 1) {
        int t = (tid >= off) ? ps[tid - off] : 0;
        __syncthreads();
        ps[tid] += t;
        __syncthreads();
    }
    int excl = ps[tid] - s;
    lrow[2 * tid] = excl;
    lrow[2 * tid + 1] = excl + a0;
    __syncthreads();

    for (int j = tid; j < nn; j += 256) {
        rowptr[n0 + j] = segBeg + lrow[j];
        int d = ldeg[j];
        invd[n0 + j] = (d > 0) ? (1.0f / (float)d) : 0.0f;
    }
    if (b == NBKT - 1 && tid == 0) rowptr[n] = e;
    __syncthreads();

    for (int i = segBeg + tid; i < segEnd; i += 256) {
        int2 ed = staging[i];
        int p = atomicAdd(&lrow[ed.y - n0], 1);
        if (p < SEG_CAP) lseg[p] = ed.x;
        else adj[segBeg + p] = ed.x;
    }
    __syncthreads();

    int m = segEnd - segBeg; if (m > SEG_CAP) m = SEG_CAP;
    for (int p = tid; p < m; p += 256) adj[segBeg + p] = lseg[p];
}

// ---------------- aggregation ----------------
// fp16-gather, EIGHT NODES PER WAVE (ladder: 50 f32 -> 46 fp16 -> 36 two-node
// -> ~30 four-node -> this). 8 lanes per node, each lane owns 8 cols via one
// 16 B load (float4 = 8 halves); 8 x 16 B = full 128 B row. One gather-load
// instruction serves EIGHT edge-rows (0.125 load-issues/edge). cvt/add per
// edge unchanged (fundamental). Divergence: per-lane loop over own node's
// degree; cost grows as max-of-8 Poisson — accepted for halved issue count.
// R4 fusion / R5 shave history in journal: gather needs high occupancy.

__global__ __launch_bounds__(256) void k_aggregate(const int* __restrict__ rowptr,
        const int* __restrict__ adj, const float* __restrict__ invd,
        const __half* __restrict__ hin16, __half* __restrict__ agg16, int n) {
    int wid = threadIdx.x >> 6, lane = threadIdx.x & 63;
    int node0 = (blockIdx.x * 4 + wid) * 8;   // 8 nodes per wave
    if (node0 >= n) return;
    const int q = lane >> 3;          // eighth 0..7 -> node slot
    const int c8 = (lane & 7) * 8;    // columns c8..c8+7
    int node = node0 + q;
    bool valid = node < n;
    int nodec = valid ? node : n - 1;
    int beg = rowptr[nodec], end = rowptr[nodec + 1];
    float a0 = 0.f, a1 = 0.f, a2 = 0.f, a3 = 0.f;
    float a4 = 0.f, a5 = 0.f, a6 = 0.f, a7 = 0.f;
    for (int e = beg; e < end; e += 8) {
        int idx[8];
        #pragma unroll
        for (int j = 0; j < 8; ++j) {
            int ee = e + j;
            idx[j] = adj[ee < end ? ee : end - 1];
        }
        float4 raw[8];
        #pragma unroll
        for (int j = 0; j < 8; ++j)
            raw[j] = *(const float4*)&hin16[(size_t)idx[j] * HID_C + c8];
        #pragma unroll
        for (int j = 0; j < 8; ++j) {
            union { float4 f; __half2 h[4]; } u;
            u.f = raw[j];
            float2 f0 = __half22float2(u.h[0]);
            float2 f1 = __half22float2(u.h[1]);
            float2 f2 = __half22float2(u.h[2]);
            float2 f3 = __half22float2(u.h[3]);
            bool in = (e + j < end);
            a0 += in ? f0.x : 0.f;  a1 += in ? f0.y : 0.f;
            a2 += in ? f1.x : 0.f;  a3 += in ? f1.y : 0.f;
            a4 += in ? f2.x : 0.f;  a5 += in ? f2.y : 0.f;
            a6 += in ? f3.x : 0.f;  a7 += in ? f3.y : 0.f;
        }
    }
    if (valid) {
        float s = invd[node];
        union { float4 f; __half2 h[4]; } o;
        o.h[0] = __floats2half2_rn(a0 * s, a1 * s);
        o.h[1] = __floats2half2_rn(a2 * s, a3 * s);
        o.h[2] = __floats2half2_rn(a4 * s, a5 * s);
        o.h[3] = __floats2half2_rn(a6 * s, a7 * s);
        *(float4*)&agg16[(size_t)node * HID_C + c8] = o.f;
    }
}

// ---------------- helpers ----------------

__device__ __forceinline__ float4 ld4(const float* p) { return *(const float4*)p; }

// ---------------- k_mm: MFMA fp16 GEMM (enc + layers) ------------------------
// R9 PROVEN core. out = relu(A @ W + b), K=128, BM=128 x BN=64, 4 waves,
// mfma_f32_16x16x32_f16, 48 KB LDS. A/B staged with the SAME assumed k-octet
// map -> HW k-permutation cancels; C/D layout col=lane&15, row=(lane>>4)*4+reg.
// R12 change: fp16-ONLY output. The f32 h was consumed by nothing except
// k_uvm's staging, which converted it with the identical __float2half — so
// dropping the f32 stores (4 x 25.6 MB) is numerically a NO-OP.
// SRC 0: A = x (f32, stride 128, converted in staging), W = Ws1 (128x64)
// SRC 1: A = [agg16 | h16] (fp16, stride 64 each), W = [Ws1;Ws2] (64x64 each)

template<int SRC>
__global__ __launch_bounds__(256, 2) void k_mm(
    const float* __restrict__ A1f,
    const __half* __restrict__ A1h, const __half* __restrict__ A2h,
    const float* __restrict__ Ws1, const float* __restrict__ Ws2,
    const float* __restrict__ bias,
    __half* __restrict__ out16, int nrows)
{
    __shared__ __half Ah[128 * 128];  // [row][k-swizzled], 32 KB
    __shared__ __half Bt[64 * 128];   // [col][k-swizzled], 16 KB
    const int t = threadIdx.x;
    const int g0 = blockIdx.x * 128;

    #pragma unroll
    for (int p = 0; p < 8; ++p) {
        int li = p * 256 + t;
        int r = li >> 4;              // 0..127
        int o = li & 15;              // octet
        int g = g0 + r; if (g > nrows - 1) g = nrows - 1;
        f16x8 v;
        if (SRC == 0) {
            const float* src = A1f + (size_t)g * 128 + o * 8;
            float4 f0 = ld4(src), f1 = ld4(src + 4);
            v[0] = (_Float16)f0.x; v[1] = (_Float16)f0.y;
            v[2] = (_Float16)f0.z; v[3] = (_Float16)f0.w;
            v[4] = (_Float16)f1.x; v[5] = (_Float16)f1.y;
            v[6] = (_Float16)f1.z; v[7] = (_Float16)f1.w;
        } else {
            const __half* src = (o < 8) ? (A1h + (size_t)g * 64 + o * 8)
                                        : (A2h + (size_t)g * 64 + (o - 8) * 8);
            v = *(const f16x8*)src;
        }
        *(f16x8*)&Ah[r * 128 + (o ^ (r & 15)) * 8] = v;
    }
    #pragma unroll
    for (int p = 0; p < 32; ++p) {
        int li = p * 256 + t;
        int c = li & 63;
        int k = li >> 6;              // 0..127
        float wv;
        if (SRC == 0) wv = Ws1[k * 64 + c];
        else          wv = (k < 64) ? Ws1[k * 64 + c] : Ws2[(k - 64) * 64 + c];
        Bt[c * 128 + (((k >> 3) ^ (c & 15)) * 8) + (k & 7)] = __float2half(wv);
    }
    __syncthreads();

    const int lane = t & 63;
    const int wid = t >> 6;
    const int R = wid * 32;           // wave's 32-row strip
    const int lr = lane & 15;
    const int lk = lane >> 4;         // octet-within-K-step

    f32x4 acc[2][4];
    #pragma unroll
    for (int fr = 0; fr < 2; ++fr)
        #pragma unroll
        for (int fc = 0; fc < 4; ++fc)
            acc[fr][fc] = (f32x4){0.f, 0.f, 0.f, 0.f};

    #pragma unroll
    for (int ks = 0; ks < 4; ++ks) {
        int o = ks * 4 + lk;          // octet 0..15
        f16x8 af0, af1;
        {
            int r0 = R + lr;
            int r1 = R + 16 + lr;
            af0 = *(const f16x8*)&Ah[r0 * 128 + (o ^ (r0 & 15)) * 8];
            af1 = *(const f16x8*)&Ah[r1 * 128 + (o ^ (r1 & 15)) * 8];
        }
        #pragma unroll
        for (int fc = 0; fc < 4; ++fc) {
            int c = fc * 16 + lr;
            f16x8 bf = *(const f16x8*)&Bt[c * 128 + (o ^ (c & 15)) * 8];
            acc[0][fc] = __builtin_amdgcn_mfma_f32_16x16x32_f16(af0, bf, acc[0][fc], 0, 0, 0);
            acc[1][fc] = __builtin_amdgcn_mfma_f32_16x16x32_f16(af1, bf, acc[1][fc], 0, 0, 0);
        }
    }

    float bv[4];
    #pragma unroll
    for (int fc = 0; fc < 4; ++fc) bv[fc] = bias[fc * 16 + lr];
    #pragma unroll
    for (int fr = 0; fr < 2; ++fr) {
        #pragma unroll
        for (int j = 0; j < 4; ++j) {
            int gr = g0 + R + fr * 16 + lk * 4 + j;
            if (gr < nrows) {
                #pragma unroll
                for (int fc = 0; fc < 4; ++fc) {
                    int col = fc * 16 + lr;
                    float v = fmaxf(acc[fr][fc][j] + bv[fc], 0.f);
                    out16[(size_t)gr * 64 + col] = __float2half(v);
                }
            }
        }
    }
}

// ---------------- k_uvm: MFMA fp16 UV GEMM (pred path) -----------------------
// U|V = h @ [W1_top | W1_bot]: K=64, tile 128x128, 4 waves, 32 KB LDS, octet
// swizzle o^(r&7), coalesced Bt staging (R11 fix), fp16 U/V out (R11).
// R12: A is now the fp16 h itself (f32 h chain deleted) — bit-identical to
// the previous stage-and-convert since the same __float2half was applied.

__global__ __launch_bounds__(256, 2) void k_uvm(
    const __half* __restrict__ H16, const float* __restrict__ W1,
    __half* __restrict__ U16, __half* __restrict__ V16, int nrows)
{
    __shared__ __half Ah[128 * 64];   // [row][k^sw], 16 KB
    __shared__ __half Bt[128 * 64];   // [col][k^sw], 16 KB
    const int t = threadIdx.x;
    const int g0 = blockIdx.x * 128;

    // stage A: 128 rows x 8 octets, fp16 direct
    #pragma unroll
    for (int p = 0; p < 4; ++p) {
        int li = p * 256 + t;         // 0..1023
        int r = li >> 3;              // 0..127
        int o = li & 7;               // octet 0..7
        int g = g0 + r; if (g > nrows - 1) g = nrows - 1;
        f16x8 v = *(const f16x8*)&H16[(size_t)g * 64 + o * 8];
        *(f16x8*)&Ah[r * 64 + (o ^ (r & 7)) * 8] = v;
    }
    // stage Bt[c][k]: c<64 -> W1[k][c] (U), c>=64 -> W1[64+k][c-64] (V).
    // COALESCED: consecutive lanes step c (contiguous W1 row halves).
    #pragma unroll
    for (int p = 0; p < 32; ++p) {
        int li = p * 256 + t;         // 0..8191 = k*128 + c
        int c = li & 127;
        int k = li >> 7;              // 0..63
        float wv = (c < 64) ? W1[k * 64 + c] : W1[(64 + k) * 64 + (c - 64)];
        Bt[c * 64 + (((k >> 3) ^ (c & 7)) * 8) + (k & 7)] = __float2half(wv);
    }
    __syncthreads();

    const int lane = t & 63;
    const int wid = t >> 6;
    const int R = wid * 32;           // wave's 32-row strip
    const int lr = lane & 15;
    const int lk = lane >> 4;

    f32x4 acc[2][8];
    #pragma unroll
    for (int fr = 0; fr < 2; ++fr)
        #pragma unroll
        for (int fc = 0; fc < 8; ++fc)
            acc[fr][fc] = (f32x4){0.f, 0.f, 0.f, 0.f};

    #pragma unroll
    for (int ks = 0; ks < 2; ++ks) {
        int o = ks * 4 + lk;          // octet 0..7
        int r0 = R + lr, r1 = R + 16 + lr;
        f16x8 af0 = *(const f16x8*)&Ah[r0 * 64 + (o ^ (r0 & 7)) * 8];
        f16x8 af1 = *(const f16x8*)&Ah[r1 * 64 + (o ^ (r1 & 7)) * 8];
        #pragma unroll
        for (int fc = 0; fc < 8; ++fc) {
            int c = fc * 16 + lr;
            f16x8 bf = *(const f16x8*)&Bt[c * 64 + (o ^ (c & 7)) * 8];
            acc[0][fc] = __builtin_amdgcn_mfma_f32_16x16x32_f16(af0, bf, acc[0][fc], 0, 0, 0);
            acc[1][fc] = __builtin_amdgcn_mfma_f32_16x16x32_f16(af1, bf, acc[1][fc], 0, 0, 0);
        }
    }

    // epilogue: fc<4 -> U16, fc>=4 -> V16 (fp16 stores)
    #pragma unroll
    for (int fr = 0; fr < 2; ++fr) {
        #pragma unroll
        for (int j = 0; j < 4; ++j) {
            int gr = g0 + R + fr * 16 + lk * 4 + j;
            if (gr < nrows) {
                #pragma unroll
                for (int fc = 0; fc < 8; ++fc) {
                    int col = fc * 16 + lr;
                    __half v = __float2half(acc[fr][fc][j]);
                    if (col < 64) U16[(size_t)gr * 64 + col] = v;
                    else          V16[(size_t)gr * 64 + (col - 64)] = v;
                }
            }
        }
    }
}

// k_pred: out[p] = relu(U[a] + V[b] + b1) . W2 + b2 — pure gather-reduce.
// fp16 U/V rows (128 B): 16 lanes x 8 B = full row. b1/W2/accum stay f32.
__global__ __launch_bounds__(256) void k_pred(
    const __half* __restrict__ U16, const __half* __restrict__ V16,
    const int* __restrict__ pidx, const float* __restrict__ b1,
    const float* __restrict__ W2, const float* __restrict__ b2,
    float* __restrict__ outp, int np)
{
    const int t = threadIdx.x;
    const int lg = t & 15;
    const int p = blockIdx.x * 16 + (t >> 4);
    float4 bv = ld4(b1 + lg * 4);
    float4 wv = ld4(W2 + lg * 4);
    if (p >= np) return;
    int2 ab = ((const int2*)pidx)[p];
    float2 ur = *(const float2*)&U16[(size_t)ab.x * 64 + lg * 4];
    float2 vr = *(const float2*)&V16[(size_t)ab.y * 64 + lg * 4];
    union { float f; __half2 h; } u0, u1, v0, v1;
    u0.f = ur.x; u1.f = ur.y; v0.f = vr.x; v1.f = vr.y;
    float2 ua = __half22float2(u0.h), ub = __half22float2(u1.h);
    float2 va = __half22float2(v0.h), vb = __half22float2(v1.h);
    float zx = fmaxf(ua.x + va.x + bv.x, 0.f);
    float zy = fmaxf(ua.y + va.y + bv.y, 0.f);
    float zz = fmaxf(ub.x + vb.x + bv.z, 0.f);
    float zw = fmaxf(ub.y + vb.y + bv.w, 0.f);
    float s = zx * wv.x + zy * wv.y + zz * wv.z + zw * wv.w;
    s += __shfl_down(s, 8, 16);
    s += __shfl_down(s, 4, 16);
    s += __shfl_down(s, 2, 16);
    s += __shfl_down(s, 1, 16);
    if (lg == 0) outp[p] = s + b2[0];
}

// ---------------- launch ----------------

extern "C" void kernel_launch(void* const* d_in, const int* in_sizes, int n_in,
                              void* d_out, int out_size, void* d_ws, size_t ws_size,
                              hipStream_t stream) {
    const float* x    = (const float*)d_in[0];
    const int*   edges= (const int*)d_in[1];
    const int*   pair = (const int*)d_in[2];
    const float* encW = (const float*)d_in[3];
    const float* encb = (const float*)d_in[4];
    const float* Wl   = (const float*)d_in[5];
    const float* bl   = (const float*)d_in[6];
    const float* Wr   = (const float*)d_in[7];
    const float* W1   = (const float*)d_in[8];
    const float* b1   = (const float*)d_in[9];
    const float* W2   = (const float*)d_in[10];
    const float* b2   = (const float*)d_in[11];
    float* out = (float*)d_out;

    const int N = N_NODES_C, E = N_EDGES_C, P = N_PAIRS_C;
    const int* dst = edges + E;
    const int M = NBKT * NB_S;

    char* w = (char*)d_ws;
    auto alloc = [&](size_t bytes) { char* p = w; w += (bytes + 255) & ~(size_t)255; return p; };
    int*   rowptr = (int*)alloc((size_t)(N + 1) * 4);
    int*   histT  = (int*)alloc((size_t)M * 4);
    int*   offs   = (int*)alloc((size_t)M * 4);
    int*   bsums  = (int*)alloc(128 * 4);
    float* invd   = (float*)alloc((size_t)N * 4);
    int*   adj    = (int*)alloc((size_t)E * 4);
    int2*  staging= (int2*)alloc((size_t)E * 8);
    __half* h16a  = (__half*)alloc((size_t)N * HID_C * 2);
    __half* h16b  = (__half*)alloc((size_t)N * HID_C * 2);
    __half* agg16 = (__half*)alloc((size_t)N * HID_C * 2);
    __half* U16   = (__half*)alloc((size_t)N * HID_C * 2);
    __half* V16   = (__half*)alloc((size_t)N * HID_C * 2);

    int nscan = (M + SCAN_ELEMS - 1) / SCAN_ELEMS;

    hipLaunchKernelGGL(k_hist, dim3(NB_S), dim3(256), 0, stream, dst, histT, E);
    hipLaunchKernelGGL(k_scan_partial, dim3(nscan), dim3(SCAN_TPB), 0, stream, histT, offs, bsums, M);
    hipLaunchKernelGGL(k_scan_blocks, dim3(1), dim3(128), 0, stream, bsums, nscan);
    hipLaunchKernelGGL(k_scan_addg, dim3((M + 255) / 256), dim3(256), 0, stream, offs, bsums, M);
    hipLaunchKernelGGL(k_scatter, dim3(NB_S), dim3(256), 0, stream, edges, offs, staging, E);
    hipLaunchKernelGGL(k_bucket_fill, dim3(NBKT), dim3(256), 0, stream, staging, offs, rowptr, invd, adj, N, E);

    const int NB128 = (N + 127) / 128;

    // encoder: MFMA fp16, fp16-only output
    k_mm<0><<<dim3(NB128), dim3(256), 0, stream>>>(
        x, nullptr, nullptr, encW, nullptr, encb, h16a, N);

    __half* h16c = h16a; __half* h16n = h16b;
    for (int l = 0; l < 3; l++) {
        // 8 nodes per wave -> 32 nodes per block
        hipLaunchKernelGGL(k_aggregate, dim3((N + 31) / 32), dim3(256), 0, stream,
                           rowptr, adj, invd, h16c, agg16, N);
        k_mm<1><<<dim3(NB128), dim3(256), 0, stream>>>(
            nullptr, agg16, h16c, Wl + (size_t)l * 64 * 64, Wr + (size_t)l * 64 * 64,
            bl + (size_t)l * 64, h16n, N);
        __half* t16 = h16c; h16c = h16n; h16n = t16;
    }

    // pred path: UV = h16 @ [W1_top | W1_bot] (MFMA fp16, fp16 out), gather-reduce.
    const int NB_UV = (N + 127) / 128;
    hipLaunchKernelGGL(k_uvm, dim3(NB_UV), dim3(256), 0, stream, h16c, W1, U16, V16, N);
    hipLaunchKernelGGL(k_pred, dim3((P + 15) / 16), dim3(256), 0, stream,
                       U16, V16, pair, b1, W2, b2, out, P);
}